// Round 2
// baseline (916.307 us; speedup 1.0000x reference)
//
#include <hip/hip_runtime.h>
#include <hip/hip_bf16.h>

#define HH 64
#define TT 24
#define NSTORE 20000
#define NREGION 2000
#define NE_SS 640000
#define NE_RS 160000
#define BN 32   // nodes per LSTM block

__device__ __forceinline__ float sigm(float x) { return 1.0f / (1.0f + __expf(-x)); }
__device__ __forceinline__ float tanh_(float x) { return 1.0f - 2.0f / (1.0f + __expf(2.0f * x)); }

// ---------------------------------------------------------------------------
// Fused LSTM over stores (blocks [0,625)) and regions (blocks [625,688)).
// Per block: BN=32 nodes, T=24 steps. WhT[k][gi] (fp32, ~64.5KB) in LDS.
// Thread (jg=tid&31, ng=tid>>5): computes gates for 4 nodes x 2 j-cols x 4 gate
// types -> owns states (4 nodes x 2 j). 32 FMA per k vs 5 LDS reads.
// LDS total ~80.5KB.
// ---------------------------------------------------------------------------
__global__ __launch_bounds__(256, 2)
void lstm_fused(const float* __restrict__ xs, const float* __restrict__ WihS,
                const float* __restrict__ WhhS, const float* __restrict__ bihS,
                const float* __restrict__ bhhS,
                const float* __restrict__ xr, const float* __restrict__ WihR,
                const float* __restrict__ WhhR, const float* __restrict__ bihR,
                const float* __restrict__ bhhR,
                float* __restrict__ hsOut, float* __restrict__ hrOut,
                int nBlocksStore)
{
    __shared__ float WhT[64][258];    // WhT[k][gi] = Whh[gi][k]; pad 258: staging 4-way not 64-way
    __shared__ float hbuf[64][36];    // hbuf[k][n], padded to 36 (16B-aligned, near-broadcast reads)
    __shared__ float xbuf[BN][25];
    __shared__ float wib[2][256];     // w_in and (bih+bhh)

    const float *x, *Wih, *Whh, *bih, *bhh;
    float* hout; int N, node0;
    if ((int)blockIdx.x < nBlocksStore) {
        x = xs; Wih = WihS; Whh = WhhS; bih = bihS; bhh = bhhS;
        hout = hsOut; N = NSTORE; node0 = blockIdx.x * BN;
    } else {
        x = xr; Wih = WihR; Whh = WhhR; bih = bihR; bhh = bhhR;
        hout = hrOut; N = NREGION; node0 = (blockIdx.x - nBlocksStore) * BN;
    }

    const int tid = threadIdx.x;

    for (int i = tid; i < 64 * 256; i += 256) {
        int gi = i >> 6, k = i & 63;
        WhT[k][gi] = Whh[i];          // coalesced global read
    }
    wib[0][tid] = Wih[tid];
    wib[1][tid] = bih[tid] + bhh[tid];
    for (int i = tid; i < BN * TT; i += 256) {
        int n = i / TT, t = i - n * TT;
        int gn = node0 + n;
        xbuf[n][t] = (gn < N) ? x[gn * TT + t] : 0.0f;
    }
    for (int i = tid; i < 64 * 36; i += 256) ((float*)hbuf)[i] = 0.0f;
    __syncthreads();

    const int jg = tid & 31, ng = tid >> 5;
    const int j0 = jg * 2, n0 = ng * 4;

    float wi0[4], wi1[4], bb0[4], bb1[4];
    #pragma unroll
    for (int g = 0; g < 4; ++g) {
        wi0[g] = wib[0][g * 64 + j0];
        wi1[g] = wib[0][g * 64 + j0 + 1];
        bb0[g] = wib[1][g * 64 + j0];
        bb1[g] = wib[1][g * 64 + j0 + 1];
    }

    float cc[4][2];
    float hh[4][2];
    #pragma unroll
    for (int dn = 0; dn < 4; ++dn)
        #pragma unroll
        for (int dj = 0; dj < 2; ++dj) cc[dn][dj] = 0.0f;

    for (int t = 0; t < TT; ++t) {
        float acc[4][2][4];   // [gate][dj][dn]
        float xv[4];
        #pragma unroll
        for (int dn = 0; dn < 4; ++dn) xv[dn] = xbuf[n0 + dn][t];
        #pragma unroll
        for (int g = 0; g < 4; ++g)
            #pragma unroll
            for (int dn = 0; dn < 4; ++dn) {
                acc[g][0][dn] = wi0[g] * xv[dn] + bb0[g];
                acc[g][1][dn] = wi1[g] * xv[dn] + bb1[g];
            }

        #pragma unroll 4
        for (int k = 0; k < 64; ++k) {
            float4 hk = *(const float4*)&hbuf[k][n0];
            float hkv[4] = {hk.x, hk.y, hk.z, hk.w};
            #pragma unroll
            for (int g = 0; g < 4; ++g) {
                float2 w = *(const float2*)&WhT[k][g * 64 + j0];
                #pragma unroll
                for (int dn = 0; dn < 4; ++dn) {
                    acc[g][0][dn] += w.x * hkv[dn];
                    acc[g][1][dn] += w.y * hkv[dn];
                }
            }
        }

        #pragma unroll
        for (int dn = 0; dn < 4; ++dn)
            #pragma unroll
            for (int dj = 0; dj < 2; ++dj) {
                float ig = sigm(acc[0][dj][dn]);
                float fg = sigm(acc[1][dj][dn]);
                float gg = tanh_(acc[2][dj][dn]);
                float og = sigm(acc[3][dj][dn]);
                float cn = fg * cc[dn][dj] + ig * gg;
                cc[dn][dj] = cn;
                hh[dn][dj] = og * tanh_(cn);
            }

        __syncthreads();   // all GEMM reads of hbuf done before overwrite
        #pragma unroll
        for (int dj = 0; dj < 2; ++dj) {
            float4 v = make_float4(hh[0][dj], hh[1][dj], hh[2][dj], hh[3][dj]);
            *(float4*)&hbuf[j0 + dj][n0] = v;
        }
        __syncthreads();   // writes visible before next step's reads
    }

    #pragma unroll
    for (int dn = 0; dn < 4; ++dn) {
        int gn = node0 + n0 + dn;
        if (gn < N) {
            float2 v = make_float2(hh[dn][0], hh[dn][1]);
            *(float2*)&hout[gn * 64 + j0] = v;
        }
    }
}

// ---------------------------------------------------------------------------
// Edge scatter: one wave per edge, lane = feature. fwd: sum[dst]+=hs[src];
// rev: sum[src]+=hs[dst]. Counts from lane 0.
// ---------------------------------------------------------------------------
__global__ __launch_bounds__(256)
void scatter_ss(const int* __restrict__ src, const int* __restrict__ dst,
                const float* __restrict__ hs,
                float* __restrict__ sumF, float* __restrict__ cntF,
                float* __restrict__ sumR, float* __restrict__ cntR)
{
    int wid = (blockIdx.x * 256 + threadIdx.x) >> 6;
    int lane = threadIdx.x & 63;
    if (wid >= NE_SS) return;
    int s = src[wid], d = dst[wid];
    float v1 = hs[s * 64 + lane];
    float v2 = hs[d * 64 + lane];
    atomicAdd(&sumF[d * 64 + lane], v1);
    atomicAdd(&sumR[s * 64 + lane], v2);
    if (lane == 0) {
        atomicAdd(&cntF[d], 1.0f);
        atomicAdd(&cntR[s], 1.0f);
    }
}

__global__ __launch_bounds__(256)
void scatter_rs(const int* __restrict__ src, const int* __restrict__ dst,
                const float* __restrict__ hr,
                float* __restrict__ sumS, float* __restrict__ cntS)
{
    int wid = (blockIdx.x * 256 + threadIdx.x) >> 6;
    int lane = threadIdx.x & 63;
    if (wid >= NE_RS) return;
    int s = src[wid], d = dst[wid];
    float v = hr[s * 64 + lane];
    atomicAdd(&sumS[d * 64 + lane], v);
    if (lane == 0) atomicAdd(&cntS[d], 1.0f);
}

// ---------------------------------------------------------------------------
// Combine: per store node (wave-per-node), fused
//   pre = 0.5*( hs@(Wself+Wr_rs)^T + mf@(0.5*Ws2d)^T + mr@(0.5*Wd2s)^T
//               + ms@Wl_rs^T + bias_c )
//   u = relu(pre + hs) ; out = u@Wf^T + bf
// Weight combine done once per block into LDS. Broadcasts via __shfl.
// ---------------------------------------------------------------------------
__global__ __launch_bounds__(256, 1)
void combine_kernel(const float* __restrict__ hs,
                    const float* __restrict__ sumF, const float* __restrict__ cntF,
                    const float* __restrict__ sumR, const float* __restrict__ cntR,
                    const float* __restrict__ sumS, const float* __restrict__ cntS,
                    const float* __restrict__ Ws2d, const float* __restrict__ bs2d,
                    const float* __restrict__ Wd2s, const float* __restrict__ bd2s,
                    const float* __restrict__ Wself, const float* __restrict__ bself,
                    const float* __restrict__ Wlrs, const float* __restrict__ blrs,
                    const float* __restrict__ Wrrs,
                    const float* __restrict__ Wfm, const float* __restrict__ bfv,
                    float* __restrict__ out, int totalWaves)
{
    __shared__ float P[64][64][4];   // 64KB, P[k][j] = {Wself+Wrrs, .5*Ws2d, .5*Wd2s, Wlrs}[j][k]
    __shared__ float WfT[64][64];    // 16KB
    __shared__ float biasc[64], bfs[64];

    const int tid = threadIdx.x;
    for (int i = tid; i < 4096; i += 256) {
        int j = i & 63, k = i >> 6;          // lanes -> consecutive j: conflict-free LDS writes
        int idx = j * 64 + k;                // W[j][k]
        float4 pv;
        pv.x = Wself[idx] + Wrrs[idx];
        pv.y = 0.5f * Ws2d[idx];             // (1-ALPHA) = 0.5
        pv.z = 0.5f * Wd2s[idx];             // ALPHA = 0.5
        pv.w = Wlrs[idx];
        *(float4*)&P[k][j][0] = pv;
        WfT[k][j] = Wfm[idx];
    }
    if (tid < 64) {
        biasc[tid] = bself[tid] + 0.5f * bs2d[tid] + 0.5f * bd2s[tid] + blrs[tid];
        bfs[tid]   = bfv[tid];
    }
    __syncthreads();

    const int lane = tid & 63;
    const int gw = (blockIdx.x * 256 + tid) >> 6;
    for (int n = gw; n < NSTORE; n += totalWaves) {
        float h  = hs[n * 64 + lane];
        float cf = fmaxf(cntF[n], 1.0f);
        float cr = fmaxf(cntR[n], 1.0f);
        float cs = fmaxf(cntS[n], 1.0f);
        float mf = sumF[n * 64 + lane] / cf;
        float mr = sumR[n * 64 + lane] / cr;
        float ms = sumS[n * 64 + lane] / cs;

        float acc = biasc[lane];
        #pragma unroll 4
        for (int k = 0; k < 64; ++k) {
            float4 pv = *(const float4*)&P[k][lane][0];
            float hk  = __shfl(h, k);
            float mfk = __shfl(mf, k);
            float mrk = __shfl(mr, k);
            float msk = __shfl(ms, k);
            acc += pv.x * hk + pv.y * mfk + pv.z * mrk + pv.w * msk;
        }
        float u = fmaxf(0.5f * acc + h, 0.0f);
        float o = bfs[lane];
        #pragma unroll 4
        for (int k = 0; k < 64; ++k) {
            o += WfT[k][lane] * __shfl(u, k);
        }
        out[n * 64 + lane] = o;
    }
}

extern "C" void kernel_launch(void* const* d_in, const int* in_sizes, int n_in,
                              void* d_out, int out_size, void* d_ws, size_t ws_size,
                              hipStream_t stream)
{
    const float* xs     = (const float*)d_in[0];
    const float* xr     = (const float*)d_in[1];
    const int*   e_ss   = (const int*)d_in[2];   // [2][640000]: row0=src, row1=dst
    const int*   rs_src = (const int*)d_in[3];
    const int*   rs_dst = (const int*)d_in[4];
    // d_in[5], d_in[6] (edge_sr_*) unused: region_h is dead code in the reference.
    const float* WihS = (const float*)d_in[7];
    const float* WhhS = (const float*)d_in[8];
    const float* bihS = (const float*)d_in[9];
    const float* bhhS = (const float*)d_in[10];
    const float* WihR = (const float*)d_in[11];
    const float* WhhR = (const float*)d_in[12];
    const float* bihR = (const float*)d_in[13];
    const float* bhhR = (const float*)d_in[14];
    const float* Ws2d = (const float*)d_in[15];
    const float* bs2d = (const float*)d_in[16];
    const float* Wd2s = (const float*)d_in[17];
    const float* bd2s = (const float*)d_in[18];
    const float* Wself = (const float*)d_in[19];
    const float* bself = (const float*)d_in[20];
    const float* Wlrs = (const float*)d_in[21];
    const float* blrs = (const float*)d_in[22];
    const float* Wrrs = (const float*)d_in[23];
    // d_in[24..26] (Wl_sr, bl_sr, Wr_sr) unused.
    const float* Wfm = (const float*)d_in[27];
    const float* bfv = (const float*)d_in[28];

    float* ws   = (float*)d_ws;
    float* hs   = ws;                 // 1,280,000 f
    float* hr   = ws + 1280000;       //   128,000 f
    float* sumF = ws + 1408000;       // 1,280,000 f
    float* sumR = ws + 2688000;       // 1,280,000 f
    float* sumS = ws + 3968000;       // 1,280,000 f
    float* cntF = ws + 5248000;       //    20,000 f
    float* cntR = ws + 5268000;       //    20,000 f
    float* cntS = ws + 5288000;       //    20,000 f
    // total 5,308,000 floats = 21.2 MB

    // zero the accumulators (sums + counts are contiguous)
    hipMemsetAsync(sumF, 0, (size_t)(3 * 1280000 + 3 * 20000) * sizeof(float), stream);

    const int storeBlocks  = (NSTORE + BN - 1) / BN;   // 625
    const int regionBlocks = (NREGION + BN - 1) / BN;  // 63
    lstm_fused<<<storeBlocks + regionBlocks, 256, 0, stream>>>(
        xs, WihS, WhhS, bihS, bhhS, xr, WihR, WhhR, bihR, bhhR, hs, hr, storeBlocks);

    scatter_ss<<<NE_SS / 4, 256, 0, stream>>>(e_ss, e_ss + NE_SS, hs, sumF, cntF, sumR, cntR);
    scatter_rs<<<NE_RS / 4, 256, 0, stream>>>(rs_src, rs_dst, hr, sumS, cntS);

    combine_kernel<<<256, 256, 0, stream>>>(hs, sumF, cntF, sumR, cntR, sumS, cntS,
                                            Ws2d, bs2d, Wd2s, bd2s, Wself, bself,
                                            Wlrs, blrs, Wrrs, Wfm, bfv,
                                            (float*)d_out, 256 * 4);
}